// Round 1
// baseline (1530.977 us; speedup 1.0000x reference)
//
#include <hip/hip_runtime.h>

// ---------------------------------------------------------------------------
// GQA + RoPE + causal attention prefill, MI355X (gfx950)
// B=2 S=2048 E=4096 HQ=32 HKV=8 D=128, SCALE = 1/64
//
// Pipeline:
//   1. convert_x   : x fp32 -> bf16, packed GEMM-A layout
//   2. tpack x4    : W fp32 (KxN) -> bf16 B^T packed layout (N-major)
//   3. gemm<bf16>  : qkv = x @ [wq|wk|wv]   (4096 x 6144)
//   4. rope        : in-place RoPE on q,k columns of qkv
//   5. vtrans      : v columns -> V_t[b][kvh][d][s]  (bf16)
//   6. attn        : flash causal attention -> packed GEMM-A layout
//   7. gemm<fp32>  : out = attn @ wo -> d_out
//
// Packed GEMM operand layout (per 128-row x 64-k block of 8192 elements):
//   flat = (blk128 * KB + kb) * 8192 + k2*1024 + row*8 + k1
//   (k = kb*64 + k2*8 + k1, row = m & 127)
// This makes global_load_lds staging linear/coalesced and ds_read_b128
// fragment reads bank-conflict-free.
// ---------------------------------------------------------------------------

typedef __bf16 bf16;
typedef __attribute__((ext_vector_type(8))) __bf16 bf16x8;
typedef __attribute__((ext_vector_type(4))) float f32x4;

#define SCALE_F 0.015625f
#define NEG_INF (-__builtin_inff())

__device__ __forceinline__ f32x4 mfma16(bf16x8 a, bf16x8 b, f32x4 c) {
  return __builtin_amdgcn_mfma_f32_16x16x32_bf16(a, b, c, 0, 0, 0);
}

__device__ __forceinline__ void gload_lds16(const void* g, void* l) {
  __builtin_amdgcn_global_load_lds(
      (const __attribute__((address_space(1))) unsigned int*)g,
      (__attribute__((address_space(3))) unsigned int*)l, 16, 0, 0);
}

// ---------------------------------------------------------------------------
// 1. x (4096 x 4096 fp32, row-major) -> packed bf16 A layout
// one thread = one 8-element (16B) packed chunk
__global__ __launch_bounds__(256) void convert_x(const float* __restrict__ x,
                                                 bf16* __restrict__ xP) {
  int p = blockIdx.x * 256 + threadIdx.x;  // chunk id, 2^21 total
  int blk = p >> 10;                        // (mb*64 + kb)
  int q = p & 1023;
  int k2 = q >> 7, row = q & 127;
  int mb = blk >> 6, kb = blk & 63;
  size_t m = (size_t)mb * 128 + row;
  size_t k = (size_t)kb * 64 + k2 * 8;
  const float* src = x + m * 4096 + k;
  float4 a = *(const float4*)(src);
  float4 b = *(const float4*)(src + 4);
  bf16x8 o;
  o[0] = (bf16)a.x; o[1] = (bf16)a.y; o[2] = (bf16)a.z; o[3] = (bf16)a.w;
  o[4] = (bf16)b.x; o[5] = (bf16)b.y; o[6] = (bf16)b.z; o[7] = (bf16)b.w;
  *(bf16x8*)(xP + (size_t)p * 8) = o;
}

// ---------------------------------------------------------------------------
// 2. W (K=4096 x Nw fp32, row-major) -> packed bf16 B^T layout at n_base
// 64(n) x 64(k) tile through LDS
__global__ __launch_bounds__(256) void tpack(const float* __restrict__ W,
                                             int Nw, int n_base,
                                             bf16* __restrict__ P) {
  __shared__ __align__(16) float tile[64][65];
  int t = threadIdx.x;
  int n0 = blockIdx.x * 64;
  int k0 = blockIdx.y * 64;
#pragma unroll
  for (int i = 0; i < 16; ++i) {
    int u = t + 256 * i;
    int kr = u >> 6, nc = u & 63;
    tile[kr][nc] = W[(size_t)(k0 + kr) * Nw + n0 + nc];
  }
  __syncthreads();
  int kb = blockIdx.y;
#pragma unroll
  for (int i = 0; i < 2; ++i) {
    int c = t + 256 * i;  // 0..511
    int k2 = c >> 6, nl = c & 63;
    int n = n_base + n0 + nl;
    bf16x8 o;
#pragma unroll
    for (int j = 0; j < 8; ++j) o[j] = (bf16)tile[k2 * 8 + j][nl];
    size_t flat = ((size_t)(n >> 7) * 64 + kb) * 8192 + k2 * 1024 + (n & 127) * 8;
    *(bf16x8*)(P + flat) = o;
  }
}

// ---------------------------------------------------------------------------
// 3/7. packed bf16 GEMM: C[128mb x 128nb] = A . B^T, fp32 accum
// 256 thr = 4 waves (2x2), 4x4 16x16 tiles per wave, BK=64 (32 MFMA/barrier)
template <int STORE_BF16>
__global__ __launch_bounds__(256) void gemm_packed(const bf16* __restrict__ Ap,
                                                   const bf16* __restrict__ Bp,
                                                   void* __restrict__ Cv,
                                                   int KB, int ldC) {
  __shared__ __align__(16) bf16 lds[16384];  // [A 8192][B 8192]
  const int t = threadIdx.x;
  const int w = t >> 6, lane = t & 63, q = lane >> 4, l15 = lane & 15;
  const int wm = w >> 1, wn = w & 1;
  const int mb = blockIdx.y, nb = blockIdx.x;

  f32x4 acc[4][4];
#pragma unroll
  for (int i = 0; i < 4; ++i)
#pragma unroll
    for (int j = 0; j < 4; ++j) acc[i][j] = (f32x4){0.f, 0.f, 0.f, 0.f};

  const bf16* Ab = Ap + (size_t)mb * KB * 8192;
  const bf16* Bb = Bp + (size_t)nb * KB * 8192;

  for (int kb = 0; kb < KB; ++kb) {
    __syncthreads();
    const bf16* ga = Ab + (size_t)kb * 8192;
    const bf16* gb = Bb + (size_t)kb * 8192;
#pragma unroll
    for (int i = 0; i < 4; ++i) {
      int c = w * 256 + i * 64;  // wave-uniform chunk base
      gload_lds16(ga + (size_t)(c + lane) * 8, (void*)&lds[c * 8]);
      gload_lds16(gb + (size_t)(c + lane) * 8, (void*)&lds[8192 + c * 8]);
    }
    __syncthreads();
#pragma unroll
    for (int s = 0; s < 2; ++s) {
      bf16x8 af[4], bfr[4];
#pragma unroll
      for (int i = 0; i < 4; ++i) {
        af[i] = *(const bf16x8*)&lds[(((s * 4 + q) << 7) + wm * 64 + i * 16 + l15) * 8];
        bfr[i] = *(const bf16x8*)&lds[8192 + (((s * 4 + q) << 7) + wn * 64 + i * 16 + l15) * 8];
      }
#pragma unroll
      for (int i = 0; i < 4; ++i)
#pragma unroll
        for (int j = 0; j < 4; ++j) acc[i][j] = mfma16(af[i], bfr[j], acc[i][j]);
    }
  }

  const int r0 = mb * 128 + wm * 64, c0 = nb * 128 + wn * 64;
  if (STORE_BF16) {
    bf16* C = (bf16*)Cv;
#pragma unroll
    for (int i = 0; i < 4; ++i)
#pragma unroll
      for (int j = 0; j < 4; ++j)
#pragma unroll
        for (int r = 0; r < 4; ++r)
          C[(size_t)(r0 + i * 16 + q * 4 + r) * ldC + c0 + j * 16 + l15] =
              (bf16)acc[i][j][r];
  } else {
    float* C = (float*)Cv;
#pragma unroll
    for (int i = 0; i < 4; ++i)
#pragma unroll
      for (int j = 0; j < 4; ++j)
#pragma unroll
        for (int r = 0; r < 4; ++r)
          C[(size_t)(r0 + i * 16 + q * 4 + r) * ldC + c0 + j * 16 + l15] =
              acc[i][j][r];
  }
}

// ---------------------------------------------------------------------------
// 4. RoPE in place on q (cols 0..4095) and k (cols 4096..5119) of qkv
__global__ __launch_bounds__(256) void rope_kernel(bf16* __restrict__ qkv,
                                                   const float* __restrict__ fr) {
  int m = blockIdx.y;                            // 0..4095  (b*S + s)
  int cp = blockIdx.x * 256 + threadIdx.x;       // 0..2559 col pair
  int col = cp * 2;
  int s = m & 2047;
  int i = (col & 127) >> 1;
  float2 cs = *(const float2*)&fr[s * 128 + i * 2];  // cos, sin
  bf16* p = qkv + (size_t)m * 6144 + col;
  float tr = (float)p[0], ti = (float)p[1];
  p[0] = (bf16)(tr * cs.x - ti * cs.y);
  p[1] = (bf16)(tr * cs.y + ti * cs.x);
}

// ---------------------------------------------------------------------------
// 5. v columns of qkv -> V_t[bkvh][d(128)][s(2048)] bf16
__global__ __launch_bounds__(256) void vtrans(const bf16* __restrict__ qkv,
                                              bf16* __restrict__ Vt) {
  __shared__ __align__(16) unsigned short tile[32 * 130];
  int t = threadIdx.x;
  int s0 = blockIdx.x * 32;
  int bkvh = blockIdx.y;
  int b = bkvh >> 3, kvh = bkvh & 7;
  const unsigned int* src = (const unsigned int*)qkv;
#pragma unroll
  for (int i = 0; i < 8; ++i) {
    int u = t + 256 * i;  // 0..2047
    int srow = u >> 6, d2 = u & 63;
    unsigned int v =
        src[(size_t)(b * 2048 + s0 + srow) * 3072 + 2560 + kvh * 64 + d2];
    *(unsigned int*)&tile[srow * 130 + 2 * d2] = v;
  }
  __syncthreads();
  unsigned int* dst = (unsigned int*)Vt;
#pragma unroll
  for (int i = 0; i < 8; ++i) {
    int u = t + 256 * i;  // 0..2047
    int d = u >> 4, s2 = u & 15;
    unsigned int lo = tile[(2 * s2) * 130 + d];
    unsigned int hi = tile[(2 * s2 + 1) * 130 + d];
    dst[(size_t)(bkvh * 128 + d) * 1024 + (s0 >> 1) + s2] = lo | (hi << 16);
  }
}

// ---------------------------------------------------------------------------
// 6. flash causal attention. 4 independent waves/block, 16 q rows each,
//    32 keys/step. Output written in packed GEMM-A layout.
__global__ __launch_bounds__(256) void attn_kernel(const bf16* __restrict__ qkv,
                                                   const bf16* __restrict__ Vt,
                                                   bf16* __restrict__ Op) {
  __shared__ __align__(16) bf16 pbuf[4][640];  // per-wave 16 x 40
  const int t = threadIdx.x;
  const int w = t >> 6, lane = t & 63, q = lane >> 4, l15 = lane & 15;
  const int bh = blockIdx.y, b = bh >> 5, h = bh & 31, kvh = h >> 2;
  const int q0w = blockIdx.x * 64 + w * 16;

  const bf16* Qb = qkv + (size_t)(b * 2048 + q0w) * 6144 + h * 128;
  bf16x8 qf[4];
#pragma unroll
  for (int tq = 0; tq < 4; ++tq)
    qf[tq] = *(const bf16x8*)(Qb + (size_t)l15 * 6144 + tq * 32 + q * 8);

  f32x4 O[8];
#pragma unroll
  for (int i = 0; i < 8; ++i) O[i] = (f32x4){0.f, 0.f, 0.f, 0.f};
  float mrow[4] = {NEG_INF, NEG_INF, NEG_INF, NEG_INF};
  float lrow[4] = {0.f, 0.f, 0.f, 0.f};

  const bf16* Kb = qkv + (size_t)(b * 2048) * 6144 + 4096 + kvh * 128;
  const bf16* Vb = Vt + (size_t)(b * 8 + kvh) * 128 * 2048;
  const int kend = q0w + 16;

  for (int kb = 0; kb < kend; kb += 32) {
    f32x4 a0 = (f32x4){0.f, 0.f, 0.f, 0.f};
    f32x4 a1 = (f32x4){0.f, 0.f, 0.f, 0.f};
#pragma unroll
    for (int tk = 0; tk < 4; ++tk) {
      bf16x8 kf0 = *(const bf16x8*)(Kb + (size_t)(kb + l15) * 6144 + tk * 32 + q * 8);
      bf16x8 kf1 = *(const bf16x8*)(Kb + (size_t)(kb + 16 + l15) * 6144 + tk * 32 + q * 8);
      a0 = mfma16(qf[tk], kf0, a0);
      a1 = mfma16(qf[tk], kf1, a1);
    }
    float alpha[4];
#pragma unroll
    for (int r = 0; r < 4; ++r) {
      float s0 = a0[r] * SCALE_F, s1 = a1[r] * SCALE_F;
      int qa = q0w + q * 4 + r;
      if (kb + l15 > qa) s0 = NEG_INF;
      if (kb + 16 + l15 > qa) s1 = NEG_INF;
      float mx = fmaxf(s0, s1);
      mx = fmaxf(mx, __shfl_xor(mx, 1));
      mx = fmaxf(mx, __shfl_xor(mx, 2));
      mx = fmaxf(mx, __shfl_xor(mx, 4));
      mx = fmaxf(mx, __shfl_xor(mx, 8));
      float mnew = fmaxf(mrow[r], mx);
      float al = __expf(mrow[r] - mnew);
      float p0 = __expf(s0 - mnew), p1 = __expf(s1 - mnew);
      float sum = p0 + p1;
      sum += __shfl_xor(sum, 1);
      sum += __shfl_xor(sum, 2);
      sum += __shfl_xor(sum, 4);
      sum += __shfl_xor(sum, 8);
      lrow[r] = lrow[r] * al + sum;
      mrow[r] = mnew;
      alpha[r] = al;
      pbuf[w][(q * 4 + r) * 40 + l15] = (bf16)p0;
      pbuf[w][(q * 4 + r) * 40 + 16 + l15] = (bf16)p1;
    }
#pragma unroll
    for (int i = 0; i < 8; ++i) {
      O[i][0] *= alpha[0];
      O[i][1] *= alpha[1];
      O[i][2] *= alpha[2];
      O[i][3] *= alpha[3];
    }
    bf16x8 pf = *(const bf16x8*)&pbuf[w][l15 * 40 + q * 8];
#pragma unroll
    for (int i = 0; i < 8; ++i) {
      bf16x8 vf = *(const bf16x8*)(Vb + (size_t)(i * 16 + l15) * 2048 + kb + q * 8);
      O[i] = mfma16(pf, vf, O[i]);
    }
  }

#pragma unroll
  for (int r = 0; r < 4; ++r) {
    float inv = 1.0f / lrow[r];
    int m = b * 2048 + q0w + q * 4 + r;
#pragma unroll
    for (int i = 0; i < 8; ++i) {
      int col = h * 128 + i * 16 + l15;
      size_t flat = ((size_t)(m >> 7) * 64 + (col >> 6)) * 8192 +
                    ((col >> 3) & 7) * 1024 + (m & 127) * 8 + (col & 7);
      Op[flat] = (bf16)(O[i][r] * inv);
    }
  }
}

// ---------------------------------------------------------------------------
extern "C" void kernel_launch(void* const* d_in, const int* in_sizes, int n_in,
                              void* d_out, int out_size, void* d_ws,
                              size_t ws_size, hipStream_t stream) {
  const float* x = (const float*)d_in[0];
  // d_in[1] = input_pos (arange(S)) — positions are s, used implicitly
  const float* fr = (const float*)d_in[2];
  const float* wq = (const float*)d_in[3];
  const float* wk = (const float*)d_in[4];
  const float* wv = (const float*)d_in[5];
  const float* wo = (const float*)d_in[6];
  float* out = (float*)d_out;
  char* ws = (char*)d_ws;

  bf16* xP = (bf16*)(ws);                        // 33,554,432 B
  bf16* WqkvP = (bf16*)(ws + 33554432ull);       // 50,331,648 B
  bf16* WoP = (bf16*)(ws + 83886080ull);         // 33,554,432 B
  bf16* qkv = (bf16*)(ws + 117440512ull);        // 50,331,648 B
  bf16* Vt = (bf16*)(ws + 167772160ull);         //  8,388,608 B
  bf16* attnP = xP;  // alias: xP dead after GEMM1, attnP born at attention

  convert_x<<<dim3(8192), dim3(256), 0, stream>>>(x, xP);
  tpack<<<dim3(64, 64), dim3(256), 0, stream>>>(wq, 4096, 0, WqkvP);
  tpack<<<dim3(16, 64), dim3(256), 0, stream>>>(wk, 1024, 4096, WqkvP);
  tpack<<<dim3(16, 64), dim3(256), 0, stream>>>(wv, 1024, 5120, WqkvP);
  tpack<<<dim3(64, 64), dim3(256), 0, stream>>>(wo, 4096, 0, WoP);
  gemm_packed<1><<<dim3(48, 32), dim3(256), 0, stream>>>(xP, WqkvP, qkv, 64, 6144);
  rope_kernel<<<dim3(10, 4096), dim3(256), 0, stream>>>(qkv, fr);
  vtrans<<<dim3(64, 16), dim3(256), 0, stream>>>(qkv, Vt);
  attn_kernel<<<dim3(32, 64), dim3(256), 0, stream>>>(qkv, Vt, attnP);
  gemm_packed<0><<<dim3(32, 32), dim3(256), 0, stream>>>(attnP, WoP, out, 64, 4096);
}

// Round 4
// 992.512 us; speedup vs baseline: 1.5425x; 1.5425x over previous
//
#include <hip/hip_runtime.h>

// ---------------------------------------------------------------------------
// GQA + RoPE + causal attention prefill, MI355X (gfx950)
// B=2 S=2048 E=4096 HQ=32 HKV=8 D=128, SCALE = 1/64
//
// Pipeline:
//   1. convert_x   : x fp32 -> bf16, packed GEMM-A layout
//   2. tpack x4    : W fp32 (KxN) -> bf16 B^T packed layout (N-major)
//   3. gemm<bf16>  : qkv = x @ [wq|wk|wv]   (4096 x 6144), pre-RoPE
//   4. kvpack      : K cols -> RoPE -> packed 64-key tiles [d8][s][d1]
//                    V cols -> transpose -> packed 64-key tiles [s8][d][s1]
//   5. attn        : flash causal attention (LDS-staged K/V tiles, Q RoPE
//                    fused in prologue) -> packed GEMM-A layout
//   6. gemm<fp32>  : out = attn @ wo -> d_out
//
// Packed GEMM operand layout (per 128-row x 64-k block of 8192 elements):
//   flat = (blk128 * KB + kb) * 8192 + k2*1024 + row*8 + k1
// K tile layout (64 keys x 128 d, 8192 elem): (d>>3)*512 + s*8 + (d&7)
// V tile layout (128 d x 64 s,  8192 elem): (s>>3)*1024 + d*8 + (s&7)
// Both make global->LDS staging a linear 16 KB copy and fragment reads
// follow the benign gemm bank pattern.
// ---------------------------------------------------------------------------

typedef __bf16 bf16;
typedef __attribute__((ext_vector_type(8))) __bf16 bf16x8;
typedef __attribute__((ext_vector_type(4))) float f32x4;

#define NEG_INF (-__builtin_inff())
#define SCLOG2E 0.02254248593737584f  /* (1/64) * log2(e) */

__device__ __forceinline__ f32x4 mfma16(bf16x8 a, bf16x8 b, f32x4 c) {
  return __builtin_amdgcn_mfma_f32_16x16x32_bf16(a, b, c, 0, 0, 0);
}

__device__ __forceinline__ void gload_lds16(const void* g, void* l) {
  __builtin_amdgcn_global_load_lds(
      (const __attribute__((address_space(1))) unsigned int*)g,
      (__attribute__((address_space(3))) unsigned int*)l, 16, 0, 0);
}

// ---------------------------------------------------------------------------
// 1. x (4096 x 4096 fp32, row-major) -> packed bf16 A layout
__global__ __launch_bounds__(256) void convert_x(const float* __restrict__ x,
                                                 bf16* __restrict__ xP) {
  int p = blockIdx.x * 256 + threadIdx.x;
  int blk = p >> 10;
  int q = p & 1023;
  int k2 = q >> 7, row = q & 127;
  int mb = blk >> 6, kb = blk & 63;
  size_t m = (size_t)mb * 128 + row;
  size_t k = (size_t)kb * 64 + k2 * 8;
  const float* src = x + m * 4096 + k;
  float4 a = *(const float4*)(src);
  float4 b = *(const float4*)(src + 4);
  bf16x8 o;
  o[0] = (bf16)a.x; o[1] = (bf16)a.y; o[2] = (bf16)a.z; o[3] = (bf16)a.w;
  o[4] = (bf16)b.x; o[5] = (bf16)b.y; o[6] = (bf16)b.z; o[7] = (bf16)b.w;
  *(bf16x8*)(xP + (size_t)p * 8) = o;
}

// ---------------------------------------------------------------------------
// 2. W (K=4096 x Nw fp32) -> packed bf16 B^T layout at n_base
__global__ __launch_bounds__(256) void tpack(const float* __restrict__ W,
                                             int Nw, int n_base,
                                             bf16* __restrict__ P) {
  __shared__ __align__(16) float tile[64][65];
  int t = threadIdx.x;
  int n0 = blockIdx.x * 64;
  int k0 = blockIdx.y * 64;
#pragma unroll
  for (int i = 0; i < 16; ++i) {
    int u = t + 256 * i;
    int kr = u >> 6, nc = u & 63;
    tile[kr][nc] = W[(size_t)(k0 + kr) * Nw + n0 + nc];
  }
  __syncthreads();
  int kb = blockIdx.y;
#pragma unroll
  for (int i = 0; i < 2; ++i) {
    int c = t + 256 * i;
    int k2 = c >> 6, nl = c & 63;
    int n = n_base + n0 + nl;
    bf16x8 o;
#pragma unroll
    for (int j = 0; j < 8; ++j) o[j] = (bf16)tile[k2 * 8 + j][nl];
    size_t flat = ((size_t)(n >> 7) * 64 + kb) * 8192 + k2 * 1024 + (n & 127) * 8;
    *(bf16x8*)(P + flat) = o;
  }
}

// ---------------------------------------------------------------------------
// 3/6. packed bf16 GEMM: C[128mb x 128nb] = A . B^T, fp32 accum
template <int STORE_BF16>
__global__ __launch_bounds__(256) void gemm_packed(const bf16* __restrict__ Ap,
                                                   const bf16* __restrict__ Bp,
                                                   void* __restrict__ Cv,
                                                   int KB, int ldC) {
  __shared__ __align__(16) bf16 lds[16384];
  const int t = threadIdx.x;
  const int w = t >> 6, lane = t & 63, q = lane >> 4, l15 = lane & 15;
  const int wm = w >> 1, wn = w & 1;
  const int mb = blockIdx.y, nb = blockIdx.x;

  f32x4 acc[4][4];
#pragma unroll
  for (int i = 0; i < 4; ++i)
#pragma unroll
    for (int j = 0; j < 4; ++j) acc[i][j] = (f32x4){0.f, 0.f, 0.f, 0.f};

  const bf16* Ab = Ap + (size_t)mb * KB * 8192;
  const bf16* Bb = Bp + (size_t)nb * KB * 8192;

  for (int kb = 0; kb < KB; ++kb) {
    __syncthreads();
    const bf16* ga = Ab + (size_t)kb * 8192;
    const bf16* gb = Bb + (size_t)kb * 8192;
#pragma unroll
    for (int i = 0; i < 4; ++i) {
      int c = w * 256 + i * 64;
      gload_lds16(ga + (size_t)(c + lane) * 8, (void*)&lds[c * 8]);
      gload_lds16(gb + (size_t)(c + lane) * 8, (void*)&lds[8192 + c * 8]);
    }
    __syncthreads();
#pragma unroll
    for (int s = 0; s < 2; ++s) {
      bf16x8 af[4], bfr[4];
#pragma unroll
      for (int i = 0; i < 4; ++i) {
        af[i] = *(const bf16x8*)&lds[(((s * 4 + q) << 7) + wm * 64 + i * 16 + l15) * 8];
        bfr[i] = *(const bf16x8*)&lds[8192 + (((s * 4 + q) << 7) + wn * 64 + i * 16 + l15) * 8];
      }
#pragma unroll
      for (int i = 0; i < 4; ++i)
#pragma unroll
        for (int j = 0; j < 4; ++j) acc[i][j] = mfma16(af[i], bfr[j], acc[i][j]);
    }
  }

  const int r0 = mb * 128 + wm * 64, c0 = nb * 128 + wn * 64;
  if (STORE_BF16) {
    bf16* C = (bf16*)Cv;
#pragma unroll
    for (int i = 0; i < 4; ++i)
#pragma unroll
      for (int j = 0; j < 4; ++j)
#pragma unroll
        for (int r = 0; r < 4; ++r)
          C[(size_t)(r0 + i * 16 + q * 4 + r) * ldC + c0 + j * 16 + l15] =
              (bf16)acc[i][j][r];
  } else {
    float* C = (float*)Cv;
#pragma unroll
    for (int i = 0; i < 4; ++i)
#pragma unroll
      for (int j = 0; j < 4; ++j)
#pragma unroll
        for (int r = 0; r < 4; ++r)
          C[(size_t)(r0 + i * 16 + q * 4 + r) * ldC + c0 + j * 16 + l15] =
              acc[i][j][r];
  }
}

// ---------------------------------------------------------------------------
// 4. kvpack: one block = one (b,kvh) x 64-key tile.
__global__ __launch_bounds__(256) void kvpack(const bf16* __restrict__ qkv,
                                              const float* __restrict__ fr,
                                              bf16* __restrict__ Kp,
                                              bf16* __restrict__ Vp) {
  __shared__ __align__(16) bf16 vt[64 * 136];
  const int t = threadIdx.x;
  const int sblk = blockIdx.x;             // 0..31
  const int bkvh = blockIdx.y;             // 0..15
  const int b = bkvh >> 3, kvh = bkvh & 7;
  const size_t tbase = ((size_t)bkvh * 32 + sblk) * 8192;
  const size_t row0 = (size_t)b * 2048 + sblk * 64;

  // --- K: rope + pack ---
#pragma unroll
  for (int it = 0; it < 4; ++it) {
    int c = it * 256 + t;                  // 0..1023
    int s_l = c >> 4, dc = c & 15;
    int s = sblk * 64 + s_l;
    bf16x8 v = *(const bf16x8*)(qkv + (row0 + s_l) * 6144 + 4096 + kvh * 128 + dc * 8);
    const float* frow = fr + (size_t)s * 128 + dc * 8;
    bf16x8 o;
#pragma unroll
    for (int p = 0; p < 4; ++p) {
      float2 cs = *(const float2*)(frow + p * 2);
      float tr = (float)v[2 * p], ti = (float)v[2 * p + 1];
      o[2 * p] = (bf16)(tr * cs.x - ti * cs.y);
      o[2 * p + 1] = (bf16)(tr * cs.y + ti * cs.x);
    }
    *(bf16x8*)(Kp + tbase + dc * 512 + s_l * 8) = o;
  }

  // --- V: load tile ---
#pragma unroll
  for (int it = 0; it < 4; ++it) {
    int c = it * 256 + t;
    int s_l = c >> 4, dc = c & 15;
    bf16x8 v = *(const bf16x8*)(qkv + (row0 + s_l) * 6144 + 5120 + kvh * 128 + dc * 8);
    *(bf16x8*)&vt[s_l * 136 + dc * 8] = v;
  }
  __syncthreads();
  // --- V: transpose + pack ---
#pragma unroll
  for (int it = 0; it < 4; ++it) {
    int c = it * 256 + t;                  // 0..1023
    int s8 = c >> 7, d = c & 127;
    bf16x8 o;
#pragma unroll
    for (int j = 0; j < 8; ++j) o[j] = vt[(s8 * 8 + j) * 136 + d];
    *(bf16x8*)(Vp + tbase + (size_t)c * 8) = o;
  }
}

// ---------------------------------------------------------------------------
// 5. flash causal attention v2.
//    grid (16 qblk, 64 bh); 4 waves x 32 q-rows; 64-key LDS-staged tiles.
__global__ __launch_bounds__(256, 2) void attn_kernel(
    const bf16* __restrict__ qkv, const bf16* __restrict__ Kp,
    const bf16* __restrict__ Vp, const float* __restrict__ fr,
    bf16* __restrict__ Op) {
  __shared__ __align__(16) bf16 ktile[8192];
  __shared__ __align__(16) bf16 vtile[8192];
  __shared__ __align__(16) bf16 pb[4][2048];

  const int t = threadIdx.x;
  const int w = t >> 6, lane = t & 63, q = lane >> 4, l15 = lane & 15;
  const int bh = blockIdx.y, b = bh >> 5, h = bh & 31, kvh = h >> 2;
  const int qb = blockIdx.x;
  const int q0 = qb * 128 + w * 32;        // wave's first q row (0..2047)

  // --- Q fragments with fused RoPE ---
  bf16x8 qf[2][4];
#pragma unroll
  for (int i = 0; i < 2; ++i) {
    int row = q0 + i * 16 + l15;
    const bf16* qrow = qkv + ((size_t)(b * 2048 + row)) * 6144 + h * 128;
    const float* frow = fr + (size_t)row * 128;
#pragma unroll
    for (int tk = 0; tk < 4; ++tk) {
      bf16x8 v = *(const bf16x8*)(qrow + tk * 32 + q * 8);
      bf16x8 o;
#pragma unroll
      for (int p = 0; p < 4; ++p) {
        float2 cs = *(const float2*)(frow + (tk * 16 + q * 4 + p) * 2);
        float tr = (float)v[2 * p], ti = (float)v[2 * p + 1];
        o[2 * p] = (bf16)(tr * cs.x - ti * cs.y);
        o[2 * p + 1] = (bf16)(tr * cs.y + ti * cs.x);
      }
      qf[i][tk] = o;
    }
  }

  f32x4 O[2][8];
#pragma unroll
  for (int i = 0; i < 2; ++i)
#pragma unroll
    for (int j = 0; j < 8; ++j) O[i][j] = (f32x4){0.f, 0.f, 0.f, 0.f};
  float mrow[2][4], lrow[2][4];
#pragma unroll
  for (int i = 0; i < 2; ++i)
#pragma unroll
    for (int r = 0; r < 4; ++r) { mrow[i][r] = NEG_INF; lrow[i][r] = 0.f; }

  const size_t kvbase = (size_t)(b * 8 + kvh) * 32;
  const int kend = qb * 128 + 128;

  for (int kb = 0; kb < kend; kb += 64) {
    __syncthreads();
    const bf16* Kt = Kp + (kvbase + (kb >> 6)) * 8192;
    const bf16* Vt = Vp + (kvbase + (kb >> 6)) * 8192;
#pragma unroll
    for (int i2 = 0; i2 < 4; ++i2) {
      int c = w * 256 + i2 * 64;           // wave-uniform chunk base
      gload_lds16(Kt + (size_t)(c + lane) * 8, (void*)&ktile[c * 8]);
      gload_lds16(Vt + (size_t)(c + lane) * 8, (void*)&vtile[c * 8]);
    }
    __syncthreads();

    if (kb <= q0 + 31) {                   // wave-uniform skip
      // --- QK^T ---
      f32x4 sc[2][4];
#pragma unroll
      for (int i = 0; i < 2; ++i)
#pragma unroll
        for (int j = 0; j < 4; ++j) sc[i][j] = (f32x4){0.f, 0.f, 0.f, 0.f};
#pragma unroll
      for (int tk = 0; tk < 4; ++tk)
#pragma unroll
        for (int jn = 0; jn < 4; ++jn) {
          bf16x8 kf = *(const bf16x8*)&ktile[(tk * 4 + q) * 512 + (jn * 16 + l15) * 8];
          sc[0][jn] = mfma16(qf[0][tk], kf, sc[0][jn]);
          sc[1][jn] = mfma16(qf[1][tk], kf, sc[1][jn]);
        }

      const bool domask = (kb + 63 > q0);
      float alpha[2][4];
#pragma unroll
      for (int i = 0; i < 2; ++i)
#pragma unroll
        for (int r = 0; r < 4; ++r) {
          int rowq = q0 + i * 16 + q * 4 + r;
          float vs[4];
          float vmax = NEG_INF;
#pragma unroll
          for (int jn = 0; jn < 4; ++jn) {
            float v = sc[i][jn][r] * SCLOG2E;
            if (domask && (kb + jn * 16 + l15 > rowq)) v = NEG_INF;
            vs[jn] = v;
            vmax = fmaxf(vmax, v);
          }
          vmax = fmaxf(vmax, __shfl_xor(vmax, 1));
          vmax = fmaxf(vmax, __shfl_xor(vmax, 2));
          vmax = fmaxf(vmax, __shfl_xor(vmax, 4));
          vmax = fmaxf(vmax, __shfl_xor(vmax, 8));
          float mn = fmaxf(mrow[i][r], vmax);
          float ms = fmaxf(mn, -1e30f);
          float al = exp2f(mrow[i][r] - ms);
          float sum = 0.f;
#pragma unroll
          for (int jn = 0; jn < 4; ++jn) {
            float p = exp2f(vs[jn] - ms);
            sum += p;
            pb[w][(2 * jn + (l15 >> 3)) * 256 + (i * 16 + q * 4 + r) * 8 + (l15 & 7)] =
                (bf16)p;
          }
          sum += __shfl_xor(sum, 1);
          sum += __shfl_xor(sum, 2);
          sum += __shfl_xor(sum, 4);
          sum += __shfl_xor(sum, 8);
          lrow[i][r] = lrow[i][r] * al + sum;
          mrow[i][r] = mn;
          alpha[i][r] = al;
        }

      // --- rescale O, P.V ---
#pragma unroll
      for (int i = 0; i < 2; ++i)
#pragma unroll
        for (int jn = 0; jn < 8; ++jn)
#pragma unroll
          for (int r = 0; r < 4; ++r) O[i][jn][r] *= alpha[i][r];
#pragma unroll
      for (int kh = 0; kh < 2; ++kh) {
        bf16x8 a0 = *(const bf16x8*)&pb[w][(kh * 4 + q) * 256 + (0 + l15) * 8];
        bf16x8 a1 = *(const bf16x8*)&pb[w][(kh * 4 + q) * 256 + (16 + l15) * 8];
#pragma unroll
        for (int jn = 0; jn < 8; ++jn) {
          bf16x8 vf = *(const bf16x8*)&vtile[(kh * 4 + q) * 1024 + (jn * 16 + l15) * 8];
          O[0][jn] = mfma16(a0, vf, O[0][jn]);
          O[1][jn] = mfma16(a1, vf, O[1][jn]);
        }
      }
    }
  }

  // --- epilogue: O/l -> packed GEMM-A layout ---
#pragma unroll
  for (int i = 0; i < 2; ++i)
#pragma unroll
    for (int r = 0; r < 4; ++r) {
      float inv = 1.0f / lrow[i][r];
      int m = b * 2048 + q0 + i * 16 + q * 4 + r;
#pragma unroll
      for (int jn = 0; jn < 8; ++jn) {
        int col = h * 128 + jn * 16 + l15;
        size_t flat = ((size_t)(m >> 7) * 64 + (col >> 6)) * 8192 +
                      ((col >> 3) & 7) * 1024 + (m & 127) * 8 + (col & 7);
        Op[flat] = (bf16)(O[i][jn][r] * inv);
      }
    }
}

// ---------------------------------------------------------------------------
extern "C" void kernel_launch(void* const* d_in, const int* in_sizes, int n_in,
                              void* d_out, int out_size, void* d_ws,
                              size_t ws_size, hipStream_t stream) {
  const float* x = (const float*)d_in[0];
  const float* fr = (const float*)d_in[2];
  const float* wq = (const float*)d_in[3];
  const float* wk = (const float*)d_in[4];
  const float* wv = (const float*)d_in[5];
  const float* wo = (const float*)d_in[6];
  float* out = (float*)d_out;
  char* ws = (char*)d_ws;

  bf16* xP = (bf16*)(ws);                    // 32 MB  [0, 32M)
  bf16* WqkvP = (bf16*)(ws + 33554432ull);   // 48 MB  [32M, 80M)
  bf16* WoP = (bf16*)(ws + 83886080ull);     // 32 MB  [80M, 112M)
  bf16* qkv = (bf16*)(ws + 117440512ull);    // 48 MB  [112M, 160M)
  // Kp/Vp alias WqkvP (dead after gemm1; kvpack runs after gemm1)
  bf16* Kp = (bf16*)(ws + 33554432ull);      // 8 MB
  bf16* Vp = (bf16*)(ws + 41943040ull);      // 8 MB
  bf16* attnP = xP;                          // alias: xP dead after gemm1

  convert_x<<<dim3(8192), dim3(256), 0, stream>>>(x, xP);
  tpack<<<dim3(64, 64), dim3(256), 0, stream>>>(wq, 4096, 0, WqkvP);
  tpack<<<dim3(16, 64), dim3(256), 0, stream>>>(wk, 1024, 4096, WqkvP);
  tpack<<<dim3(16, 64), dim3(256), 0, stream>>>(wv, 1024, 5120, WqkvP);
  tpack<<<dim3(64, 64), dim3(256), 0, stream>>>(wo, 4096, 0, WoP);
  gemm_packed<1><<<dim3(48, 32), dim3(256), 0, stream>>>(xP, WqkvP, qkv, 64, 6144);
  kvpack<<<dim3(32, 16), dim3(256), 0, stream>>>(qkv, fr, Kp, Vp);
  attn_kernel<<<dim3(16, 64), dim3(256), 0, stream>>>(qkv, Kp, Vp, fr, attnP);
  gemm_packed<0><<<dim3(32, 32), dim3(256), 0, stream>>>(attnP, WoP, out, 64, 4096);
}